// Round 13
// baseline (100.654 us; speedup 1.0000x reference)
//
#include <hip/hip_runtime.h>
#include <math.h>

#define NS 4096
#define NC 500
#define NF 256
#define NK 400
#define KC_GEMM 16     // split-K chunks (256 rows each)
#define KC_CS   32     // K chunks for colsum (128 rows each)

#define NB_GEMM (32 * KC_GEMM * 2)        // 1024 blocks
#define NB_CS   (KC_CS * 2)               // 64 blocks
#define NB_OTH  (NB_GEMM + NB_CS)         // 1088
#define NB_QUE  ((NC * NF) / 32)          // 4000 blocks (4 waves x 8 rows each)

// ---------------- kernel 1: fused heavy pass (R8 layout, 4c x 4f GEMM tile) -
// Contiguous job mapping [0,1024) gemm | [1024,1088) colsum | queue — the
// measured best (R5/R8); all interleave/stagger schemes regressed (R6/R7/
// R9/R10/R11). GEMM inner tile changed 16c x 1f -> 4c x 4f: per wave per n,
// ONE uniform ds_read_b128 (was 4) + one coalesced dwordx4 X load + 16 FMA.
// R8's version issued 4 broadcast LDS reads per 16 FMA; with 16 waves/CU on
// one LDS pipe that was the GEMM-phase bottleneck.
__global__ __launch_bounds__(256) void k_heavy(
    const float* __restrict__ Xs, const float* __restrict__ Ys, float* __restrict__ Ps,
    const float* __restrict__ Xt, const float* __restrict__ Yt, float* __restrict__ Pt,
    float* __restrict__ CSs, float* __restrict__ CSt,
    const float* __restrict__ queue, const int* __restrict__ qsize,
    float* __restrict__ qsum) {
  __shared__ float ytile[256][16];              // 16 KB (gemm blocks only)
  const int bid  = blockIdx.x;
  const int tid  = threadIdx.x;
  const int w    = tid >> 6;
  const int lane = tid & 63;

  if (bid < NB_GEMM) {
    // ---- GEMM partials: P[kc][c0..c0+15][f] = sum_{n in chunk} Y[n,c]*X[n,f]
    const int z   = bid >> 9;                   // 0:src 1:tgt
    const int rem = bid & 511;
    const int kc  = rem >> 5;
    const int c0  = (rem & 31) * 16;
    const float* X = z ? Xt : Xs;
    const float* Y = z ? Yt : Ys;
    float*       P = z ? Pt : Ps;
    const int n0   = kc * 256;
    const int cmax = (NC - c0 < 16) ? (NC - c0) : 16;

    for (int i = tid; i < 256 * 16; i += 256) {
      int rr = i >> 4, cc = i & 15;
      ytile[rr][cc] = (cc < cmax) ? Y[(size_t)(n0 + rr) * NC + c0 + cc] : 0.f;
    }
    __syncthreads();

    // thread tile: wave (= cg) owns classes c0+cg*4..+3, lane owns 4 features
    const int cg = w;
    const int f4 = lane * 4;
    float4 a0 = make_float4(0.f, 0.f, 0.f, 0.f);   // class cg*4+0, features f4..f4+3
    float4 a1 = make_float4(0.f, 0.f, 0.f, 0.f);
    float4 a2 = make_float4(0.f, 0.f, 0.f, 0.f);
    float4 a3 = make_float4(0.f, 0.f, 0.f, 0.f);
    const float* Xp = X + (size_t)n0 * NF + f4;

    #pragma unroll 4
    for (int n = 0; n < 256; ++n) {
      float4 xv = *reinterpret_cast<const float4*>(Xp + (size_t)n * NF);
      float4 yv = *reinterpret_cast<const float4*>(&ytile[n][cg * 4]);  // uniform b128
      a0.x = fmaf(yv.x, xv.x, a0.x); a0.y = fmaf(yv.x, xv.y, a0.y);
      a0.z = fmaf(yv.x, xv.z, a0.z); a0.w = fmaf(yv.x, xv.w, a0.w);
      a1.x = fmaf(yv.y, xv.x, a1.x); a1.y = fmaf(yv.y, xv.y, a1.y);
      a1.z = fmaf(yv.y, xv.z, a1.z); a1.w = fmaf(yv.y, xv.w, a1.w);
      a2.x = fmaf(yv.z, xv.x, a2.x); a2.y = fmaf(yv.z, xv.y, a2.y);
      a2.z = fmaf(yv.z, xv.z, a2.z); a2.w = fmaf(yv.z, xv.w, a2.w);
      a3.x = fmaf(yv.w, xv.x, a3.x); a3.y = fmaf(yv.w, xv.y, a3.y);
      a3.z = fmaf(yv.w, xv.z, a3.z); a3.w = fmaf(yv.w, xv.w, a3.w);
    }

    float* Pb = &P[((size_t)kc * NC + c0 + cg * 4) * NF + f4];
    if (c0 + cg * 4 + 0 < NC) *reinterpret_cast<float4*>(Pb + 0 * NF) = a0;
    if (c0 + cg * 4 + 1 < NC) *reinterpret_cast<float4*>(Pb + 1 * NF) = a1;
    if (c0 + cg * 4 + 2 < NC) *reinterpret_cast<float4*>(Pb + 2 * NF) = a2;
    if (c0 + cg * 4 + 3 < NC) *reinterpret_cast<float4*>(Pb + 3 * NF) = a3;

  } else if (bid < NB_OTH) {
    // ---- column sums: CS[kc][c] = sum_{n in chunk} Y[n,c]
    const int b = bid - NB_GEMM;
    const float* Y = (b >> 5) ? Yt : Ys;
    float*      CS = (b >> 5) ? CSt : CSs;
    const int kc = b & 31;
    const int n0 = kc * (NS / KC_CS);
    const int t  = tid;
    float s0 = 0.f, s1 = 0.f;
    for (int n = n0; n < n0 + NS / KC_CS; ++n) {
      const float* row = Y + (size_t)n * NC;
      s0 += row[t];
      if (t + 256 < NC) s1 += row[t + 256];
    }
    CS[kc * 512 + t] = s0;
    if (t + 256 < NC) CS[kc * 512 + t + 256] = s1;

  } else {
    // ---- masked queue reduction, tail-skip, 8 rows per wave (R8-proven) ----
    const int qb = bid - NB_OTH;
    const int r0 = (qb * 4 + w) * 8;            // 8 consecutive rows, one class
    const int c  = r0 >> 8;
    const int qs = qsize[c];
    const int L  = (qs + 3) >> 2;               // float4s needed (<=100)
    const float* base = queue + (size_t)r0 * NK;
    float s0 = 0.f, s1 = 0.f, s2 = 0.f, s3 = 0.f;
    float s4 = 0.f, s5 = 0.f, s6 = 0.f, s7 = 0.f;

    if (lane < L) {
      const int k = 4 * lane;                   // 0..255, k < qs guaranteed
      float4 v0 = *reinterpret_cast<const float4*>(base + 0 * NK + k);
      float4 v1 = *reinterpret_cast<const float4*>(base + 1 * NK + k);
      float4 v2 = *reinterpret_cast<const float4*>(base + 2 * NK + k);
      float4 v3 = *reinterpret_cast<const float4*>(base + 3 * NK + k);
      float4 v4 = *reinterpret_cast<const float4*>(base + 4 * NK + k);
      float4 v5 = *reinterpret_cast<const float4*>(base + 5 * NK + k);
      float4 v6 = *reinterpret_cast<const float4*>(base + 6 * NK + k);
      float4 v7 = *reinterpret_cast<const float4*>(base + 7 * NK + k);
      s0 += v0.x; s1 += v1.x; s2 += v2.x; s3 += v3.x;
      s4 += v4.x; s5 += v5.x; s6 += v6.x; s7 += v7.x;
      if (k + 1 < qs) { s0 += v0.y; s1 += v1.y; s2 += v2.y; s3 += v3.y;
                        s4 += v4.y; s5 += v5.y; s6 += v6.y; s7 += v7.y; }
      if (k + 2 < qs) { s0 += v0.z; s1 += v1.z; s2 += v2.z; s3 += v3.z;
                        s4 += v4.z; s5 += v5.z; s6 += v6.z; s7 += v7.z; }
      if (k + 3 < qs) { s0 += v0.w; s1 += v1.w; s2 += v2.w; s3 += v3.w;
                        s4 += v4.w; s5 += v5.w; s6 += v6.w; s7 += v7.w; }
    }
    if (lane + 64 < L) {
      const int k = 256 + 4 * lane;             // 256..399
      float4 v0 = *reinterpret_cast<const float4*>(base + 0 * NK + k);
      float4 v1 = *reinterpret_cast<const float4*>(base + 1 * NK + k);
      float4 v2 = *reinterpret_cast<const float4*>(base + 2 * NK + k);
      float4 v3 = *reinterpret_cast<const float4*>(base + 3 * NK + k);
      float4 v4 = *reinterpret_cast<const float4*>(base + 4 * NK + k);
      float4 v5 = *reinterpret_cast<const float4*>(base + 5 * NK + k);
      float4 v6 = *reinterpret_cast<const float4*>(base + 6 * NK + k);
      float4 v7 = *reinterpret_cast<const float4*>(base + 7 * NK + k);
      s0 += v0.x; s1 += v1.x; s2 += v2.x; s3 += v3.x;
      s4 += v4.x; s5 += v5.x; s6 += v6.x; s7 += v7.x;
      if (k + 1 < qs) { s0 += v0.y; s1 += v1.y; s2 += v2.y; s3 += v3.y;
                        s4 += v4.y; s5 += v5.y; s6 += v6.y; s7 += v7.y; }
      if (k + 2 < qs) { s0 += v0.z; s1 += v1.z; s2 += v2.z; s3 += v3.z;
                        s4 += v4.z; s5 += v5.z; s6 += v6.z; s7 += v7.z; }
      if (k + 3 < qs) { s0 += v0.w; s1 += v1.w; s2 += v2.w; s3 += v3.w;
                        s4 += v4.w; s5 += v5.w; s6 += v6.w; s7 += v7.w; }
    }
    #pragma unroll
    for (int m = 32; m; m >>= 1) {
      s0 += __shfl_xor(s0, m); s1 += __shfl_xor(s1, m);
      s2 += __shfl_xor(s2, m); s3 += __shfl_xor(s3, m);
      s4 += __shfl_xor(s4, m); s5 += __shfl_xor(s5, m);
      s6 += __shfl_xor(s6, m); s7 += __shfl_xor(s7, m);
    }
    if (lane == 0) {
      *reinterpret_cast<float4*>(&qsum[r0])     = make_float4(s0, s1, s2, s3);
      *reinterpret_cast<float4*>(&qsum[r0 + 4]) = make_float4(s4, s5, s6, s7);
    }
  }
}

// ---------------- kernel 2: finalize means + intra diagonal ----------------
// one class per block (500 blocks, full-machine grid), thread f = feature f
__global__ __launch_bounds__(256) void k_means(
    const float* __restrict__ qsum, const int* __restrict__ qsize,
    const float* __restrict__ Psrc, const float* __restrict__ Ptgt,
    const float* __restrict__ CSsrc, const float* __restrict__ CStgt,
    float* __restrict__ MS, float* __restrict__ MT, float* __restrict__ ipart) {
  const int c = blockIdx.x;
  const int f = threadIdx.x;

  float cs_s = 0.f, cs_t = 0.f;
  #pragma unroll
  for (int kc = 0; kc < KC_CS; ++kc) {          // wave-uniform -> s_load
    cs_s += CSsrc[kc * 512 + c];
    cs_t += CStgt[kc * 512 + c];
  }
  float num = (float)qsize[c];
  float ns = qsum[(size_t)c * NF + f];
  float nt = 0.f;
  #pragma unroll
  for (int kc = 0; kc < KC_GEMM; ++kc) {
    ns += Psrc[((size_t)kc * NC + c) * NF + f];
    nt += Ptgt[((size_t)kc * NC + c) * NF + f];
  }
  float ms = ns / (num + cs_s + 1e-8f);
  float mt = nt / (cs_t + 1e-8f);
  MS[(size_t)c * NF + f] = ms;
  MT[(size_t)c * NF + f] = mt;

  float d = ms - mt;
  float s = d * d;
  #pragma unroll
  for (int m = 32; m; m >>= 1) s += __shfl_xor(s, m);
  __shared__ float red[4];
  int wid = f >> 6, lane = f & 63;
  if (lane == 0) red[wid] = s;
  __syncthreads();
  if (f == 0) ipart[c] = sqrtf(fmaxf(red[0] + red[1] + red[2] + red[3], 1e-12f));
}

// ---------------- kernel 3: pairwise distances (16x16 tiles) ----------------
#define TC 16
#define NBT 32                              // ceil(500/16)
__global__ __launch_bounds__(256) void k_dist(const float* __restrict__ MS,
                                              float* __restrict__ epart) {
  __shared__ float a[TC][NF + 4];
  __shared__ float b[TC][NF + 4];
  const int bi = blockIdx.x & (NBT - 1);
  const int bj = blockIdx.x >> 5;

  for (int i = threadIdx.x; i < TC * (NF / 4); i += 256) {
    int rr = i >> 6, fq = (i & 63) * 4;
    int c1 = bi * TC + rr;
    int c2 = bj * TC + rr;
    float4 va = (c1 < NC) ? *reinterpret_cast<const float4*>(&MS[(size_t)c1 * NF + fq])
                          : make_float4(0.f, 0.f, 0.f, 0.f);
    float4 vb = (c2 < NC) ? *reinterpret_cast<const float4*>(&MS[(size_t)c2 * NF + fq])
                          : make_float4(0.f, 0.f, 0.f, 0.f);
    *reinterpret_cast<float4*>(&a[rr][fq]) = va;
    *reinterpret_cast<float4*>(&b[rr][fq]) = vb;
  }
  __syncthreads();

  const int i1 = threadIdx.x >> 4, i2 = threadIdx.x & 15;
  float s = 0.f;
  #pragma unroll 8
  for (int fq = 0; fq < NF; fq += 4) {
    float4 va = *reinterpret_cast<const float4*>(&a[i1][fq]);
    float4 vb = *reinterpret_cast<const float4*>(&b[i2][fq]);
    float d0 = va.x - vb.x, d1 = va.y - vb.y, d2 = va.z - vb.z, d3 = va.w - vb.w;
    s = fmaf(d0, d0, s); s = fmaf(d1, d1, s); s = fmaf(d2, d2, s); s = fmaf(d3, d3, s);
  }
  bool valid = (bi * TC + i1 < NC) && (bj * TC + i2 < NC);
  float rr = valid ? sqrtf(fmaxf(s, 1e-12f)) : 0.f;

  #pragma unroll
  for (int m = 32; m; m >>= 1) rr += __shfl_xor(rr, m);
  __shared__ float red[4];
  int wid = threadIdx.x >> 6, lane = threadIdx.x & 63;
  if (lane == 0) red[wid] = rr;
  __syncthreads();
  if (threadIdx.x == 0) epart[blockIdx.x] = red[0] + red[1] + red[2] + red[3];
}

// ---------------- kernel 4: final scalars ----------------
__global__ __launch_bounds__(1024) void k_final(const float* __restrict__ ipart,
                                                const float* __restrict__ epart,
                                                float* __restrict__ out) {
  const int t = threadIdx.x;                // 1024 threads
  float si = (t < NC) ? ipart[t] : 0.f;
  float se = epart[t];
  #pragma unroll
  for (int m = 32; m; m >>= 1) { si += __shfl_xor(si, m); se += __shfl_xor(se, m); }
  __shared__ float ri[16], re[16];
  int wid = t >> 6, lane = t & 63;
  if (lane == 0) { ri[wid] = si; re[wid] = se; }
  __syncthreads();
  if (t == 0) {
    float A = 0.f, B = 0.f;
    #pragma unroll
    for (int w2 = 0; w2 < 16; ++w2) { A += ri[w2]; B += re[w2]; }
    out[0] = A / (float)NC;
    out[1] = B / ((float)NC * (float)NC);
  }
}

extern "C" void kernel_launch(void* const* d_in, const int* in_sizes, int n_in,
                              void* d_out, int out_size, void* d_ws, size_t ws_size,
                              hipStream_t stream) {
  const float* src_x = (const float*)d_in[0];
  const float* tgt_x = (const float*)d_in[1];
  const float* src_y = (const float*)d_in[2];
  const float* tgt_y = (const float*)d_in[3];
  const float* queue = (const float*)d_in[4];
  const int*   qsize = (const int*)d_in[5];
  float* out = (float*)d_out;

  float* ws    = (float*)d_ws;
  float* qsum  = ws;                                   // 128000
  float* Psrc  = qsum + NC * NF;                       // 16 * 128000
  float* Ptgt  = Psrc + (size_t)KC_GEMM * NC * NF;     // 16 * 128000
  float* CSs   = Ptgt + (size_t)KC_GEMM * NC * NF;     // 32 * 512
  float* CSt   = CSs + KC_CS * 512;                    // 32 * 512
  float* MS    = CSt + KC_CS * 512;                    // 128000
  float* MT    = MS + NC * NF;                         // 128000
  float* ipart = MT + NC * NF;                         // 500
  float* epart = ipart + NC;                           // 1024

  // 1) fused heavy pass: gemm + colsum + queue (contiguous, R8 layout)
  k_heavy<<<NB_OTH + NB_QUE, 256, 0, stream>>>(
      src_x, src_y, Psrc, tgt_x, tgt_y, Ptgt, CSs, CSt, queue, qsize, qsum);

  // 2) means + intra diagonal (one class per block)
  k_means<<<NC, 256, 0, stream>>>(qsum, qsize, Psrc, Ptgt, CSs, CSt, MS, MT, ipart);

  // 3) pairwise distances
  k_dist<<<NBT * NBT, 256, 0, stream>>>(MS, epart);

  // 4) final reduction
  k_final<<<1, 1024, 0, stream>>>(ipart, epart, out);
}